// Round 12
// baseline (579.694 us; speedup 1.0000x reference)
//
#include <hip/hip_runtime.h>
#include <hip/hip_bf16.h>

#define BB   2
#define NN   128
#define SS   4
#define DGG  8
#define CIN  4
#define COUT 8
#define HH   32
#define NTHR 512

typedef __attribute__((ext_vector_type(4))) float          fvec4;
typedef __attribute__((ext_vector_type(4))) unsigned short usvec4;
typedef __attribute__((ext_vector_type(8))) unsigned short usvec8;
typedef __attribute__((ext_vector_type(2))) __fp16         half2v;
typedef __attribute__((ext_vector_type(8))) __fp16         f16x8;
typedef __attribute__((ext_vector_type(4))) float          f32x4;
typedef __attribute__((ext_vector_type(4))) unsigned int   uvec4;

__device__ __forceinline__ float bf2f(unsigned short u) {
    return __uint_as_float(((unsigned int)u) << 16);
}
__device__ __forceinline__ float silu_f(float x) {
    float e = __builtin_amdgcn_exp2f(x * -1.44269504f);
    return x * __builtin_amdgcn_rcpf(1.0f + e);
}
__device__ __forceinline__ float exp_f(float x) {
    return __builtin_amdgcn_exp2f(x * 1.44269504f);
}

#if __has_builtin(__builtin_amdgcn_fdot2)
__device__ __forceinline__ float FDOT2(half2v a, half2v b, float c) {
    return __builtin_amdgcn_fdot2(a, b, c, false);
}
#else
__device__ __forceinline__ float FDOT2(half2v a, half2v b, float c) {
    return (float)a[0] * (float)b[0] + (float)a[1] * (float)b[1] + c;
}
#endif

__device__ __forceinline__ half2v upk(unsigned int u) {
    union { unsigned int u; half2v h; } x; x.u = u; return x.h;
}
__device__ __forceinline__ unsigned int pk2u(float a, float b) {
#if __has_builtin(__builtin_amdgcn_cvt_pkrtz)
    half2v h = __builtin_amdgcn_cvt_pkrtz(a, b);
#else
    half2v h; h[0] = (__fp16)a; h[1] = (__fp16)b;
#endif
    union { half2v h; unsigned int u; } x; x.h = h; return x.u;
}
union FU { uvec4 u; f16x8 h; };
__device__ __forceinline__ f16x8 mk_frag(unsigned a, unsigned b, unsigned c, unsigned d) {
    FU x; x.u = (uvec4){a, b, c, d}; return x.h;
}

__device__ __forceinline__ float loadS(const void* p, int idx, int fmode) {
    return fmode ? bf2f(((const unsigned short*)p)[idx])
                 : ((const float*)p)[idx];
}
__device__ __forceinline__ void load8(const void* p, int base, int fmode, float* dst) {
    if (fmode) {
        usvec8 v = *(const usvec8*)((const unsigned short*)p + base);
#pragma unroll
        for (int d = 0; d < 8; ++d) dst[d] = bf2f(v[d]);
    } else {
        fvec4 a = *(const fvec4*)((const float*)p + base);
        fvec4 b = *(const fvec4*)((const float*)p + base + 4);
        dst[0] = a[0]; dst[1] = a[1]; dst[2] = a[2]; dst[3] = a[3];
        dst[4] = b[0]; dst[5] = b[1]; dst[6] = b[2]; dst[7] = b[3];
    }
}
// 8 consecutive weights -> f16x8 MFMA fragment (element r = k offset r)
__device__ __forceinline__ f16x8 load_row8(const void* p, int eoff, int fmode) {
    unsigned u[4];
    if (fmode) {
        usvec8 v = *(const usvec8*)((const unsigned short*)p + eoff);
#pragma unroll
        for (int q = 0; q < 4; ++q) u[q] = pk2u(bf2f(v[2 * q]), bf2f(v[2 * q + 1]));
    } else {
        fvec4 a = *(const fvec4*)((const float*)p + eoff);
        fvec4 b = *(const fvec4*)((const float*)p + eoff + 4);
        u[0] = pk2u(a[0], a[1]); u[1] = pk2u(a[2], a[3]);
        u[2] = pk2u(b[0], b[1]); u[3] = pk2u(b[2], b[3]);
    }
    return mk_frag(u[0], u[1], u[2], u[3]);
}
__device__ __forceinline__ int load_mask(const void* p, int idx, int mmode) {
    if (mmode == 0) return ((const int*)p)[idx] != 0;
    if (mmode == 1) return ((const unsigned short*)p)[idx] != 0;
    if (mmode == 2) return ((const unsigned char*)p)[idx] != 0;
    return ((const unsigned int*)p)[idx] != 0;
}
__device__ __forceinline__ void stage_pk(unsigned int* dst, const void* src,
                                         int pairs, int fmode, int tid) {
    if (fmode) {
        const unsigned short* s = (const unsigned short*)src;
        for (int x = tid; x < pairs; x += NTHR)
            dst[x] = pk2u(bf2f(s[2 * x]), bf2f(s[2 * x + 1]));
    } else {
        const float* s = (const float*)src;
        for (int x = tid; x < pairs; x += NTHR)
            dst[x] = pk2u(s[2 * x], s[2 * x + 1]);
    }
}
__device__ __forceinline__ void copy_arr(float* sm, const void* src, int off,
                                         int cnt, int fmode, int tid) {
    if (fmode) {
        const unsigned short* s = (const unsigned short*)src;
        for (int x = tid; x < cnt; x += NTHR) sm[off + x] = bf2f(s[x]);
    } else {
        const float* s = (const float*)src;
        for (int x = tid; x < cnt; x += NTHR) sm[off + x] = s[x];
    }
}
// modes: [0]=float dtype (0=f32,1=bf16), [1]=mask dtype (0=i32,1=bf16,2=u8,3=f32)
__device__ __forceinline__ void detect_inline(const void* g_mask, const void* g_coset,
                                              int tid, int* smi, int slot) {
    if (tid < 64) {
        const unsigned short* cu = (const unsigned short*)g_coset;
        unsigned short v = cu[2 * tid];
        int e = (v >> 7) & 0xFF;
        int hits = __popcll(__ballot(e >= 110 && e <= 135));
        int fmode_ = (hits > 32) ? 1 : 0;
        const unsigned short* mu = (const unsigned short*)g_mask;
        int evenBF = 0, any3 = 0, anyByte = 0;
        for (int r = 0; r < 8; ++r) {
            int idx = tid + r * 64;
            unsigned short m = mu[idx];
            if (m == 0x3F80) { any3 = 1; if (!(idx & 1)) evenBF = 1; }
            if (m == 0x0101 || m == 0x0100) anyByte = 1;
        }
        evenBF  = (__ballot(evenBF)  != 0ull);
        any3    = (__ballot(any3)    != 0ull);
        anyByte = (__ballot(anyByte) != 0ull);
        if (tid == 0) {
            smi[slot]     = fmode_;
            smi[slot + 1] = evenBF ? 1 : (any3 ? 3 : (anyByte ? 2 : 0));
        }
    }
}

// LDS layout (u32 units)
#define UG_G    0      // 2048: pairwise_g slice for (bn,s1), packed f16 [pos][4]
#define F_FA    2048   // 2048 f32: coset b-slice [pos2=n*4+s][ci]
#define U_MASK  4096   // 512: key mask per pos (0/1)
#define U_YW1   4608   // 128 pairs (w0,w1) per (ci,j1)
#define U_GW1   4736   // 512 pairs: [ci][j1][4]
#define F_YB1   5248   // 128
#define F_YB2   5376   // 128
#define F_YW3   5504   // 128
#define F_GB1   5632   // 128
#define F_GB2   5760   // 128
#define F_GW3   5888   // 128
#define F_YB3   6016   // 4
#define F_GB3   6020   // 4
#define F_RED   6024   // 64: [8 waves][4 ci][N,D]
#define F_MODE  6088   // 2
#define U_TOTAL 6090   // ~24.4 KB

// One block per (bn, s1); NOW 512 threads = 8 waves; each wave handles 4
// position-tiles of 16 (round 10: 4 waves x 8 tiles).  Body is the EXACT
// round-10 per-tile chain (64 VGPR, no spill).  Round-11's unroll-2 + hoisting
// blew the register budget (WRITE_SIZE 27KB -> 326MB scratch) — reverted.
// TLP instead of ILP: 64-VGPR body supports 8 waves/SIMD; 512-thread blocks
// at 4 blocks/CU give 32 waves/CU (round 10: 16), filling the idle issue
// slots that showed as VALUBusy=61%.
__global__ __launch_bounds__(NTHR, 8) void emha_mfma(
    const void* __restrict__ g_pw, const void* __restrict__ g_coset,
    const void* __restrict__ g_mask,
    const void* yW1, const void* yb1, const void* yW2, const void* yb2,
    const void* yW3, const void* yb3,
    const void* gW1, const void* gb1, const void* gW2, const void* gb2,
    const void* gW3, const void* gb3,
    const void* wout, void* outp)
{
    __shared__ unsigned int smu[U_TOTAL];
    float* smf = (float*)smu;
    int*   smi = (int*)smu;
    const int tid = threadIdx.x;

    detect_inline(g_mask, g_coset, tid, smi, F_MODE);
    __syncthreads();
    const int fmode = smi[F_MODE];
    const int mmode = smi[F_MODE + 1];
    __syncthreads();

    const int bn = blockIdx.x >> 2;   // b*128 + n1
    const int s1 = blockIdx.x & 3;
    const int b  = bn >> 7;
    const int n1 = bn & 127;

    // ---- stage pairwise_g slice (pos = n2*4+s2), packed f16, b128 writes ----
    {
        const int pos = tid;          // 512 threads cover all 512 positions
        const int n2 = pos >> 2, s2 = pos & 3;
        float g8[8];
        load8(g_pw, (((bn * NN + n2) * SS + s1) * SS + s2) * DGG, fmode, g8);
        uvec4 gp;
#pragma unroll
        for (int q = 0; q < 4; ++q) gp[q] = pk2u(g8[2 * q], g8[2 * q + 1]);
        *(uvec4*)&smu[UG_G + pos * 4] = gp;
    }
    // ---- stage coset b-slice (f32) and key mask ----
    for (int x = tid; x < 2048; x += NTHR)
        smf[F_FA + x] = loadS(g_coset, b * 2048 + x, fmode);
    smu[U_MASK + tid] = (unsigned)load_mask(g_mask, b * 512 + tid, mmode);
    // ---- stage W1s (packed pairs) + biases/w3 (f32) ----
    stage_pk(&smu[U_YW1], yW1, 128, fmode, tid);
    stage_pk(&smu[U_GW1], gW1, 512, fmode, tid);
    copy_arr(smf, yb1, F_YB1, 128, fmode, tid);
    copy_arr(smf, yb2, F_YB2, 128, fmode, tid);
    copy_arr(smf, yW3, F_YW3, 128, fmode, tid);
    copy_arr(smf, gb1, F_GB1, 128, fmode, tid);
    copy_arr(smf, gb2, F_GB2, 128, fmode, tid);
    copy_arr(smf, gW3, F_GW3, 128, fmode, tid);
    copy_arr(smf, yb3, F_YB3, 4, fmode, tid);
    copy_arr(smf, gb3, F_GB3, 4, fmode, tid);
    __syncthreads();

    const int lane = tid & 63;
    const int wave = tid >> 6;        // [0,8)
    const int quad = lane >> 4;
    const int col  = lane & 15;
    const int qpos = n1 * 4 + s1;     // query index in b-slice

    float accN[4] = {0.f, 0.f, 0.f, 0.f};
    float accD[4] = {0.f, 0.f, 0.f, 0.f};
    const f32x4 zf = {0.f, 0.f, 0.f, 0.f};

#pragma unroll
    for (int ci = 0; ci < CIN; ++ci) {
        const float fb = smf[F_FA + qpos * 4 + ci];
        // ky L1 constants for this lane's 8 j1 rows (j1 = quad*8 + jj)
        float w0f[8], cc[8], b1g[8];
        {
            uvec4 pa = *(const uvec4*)&smu[U_YW1 + ci * 32 + quad * 8];
            uvec4 pb = *(const uvec4*)&smu[U_YW1 + ci * 32 + quad * 8 + 4];
            fvec4 ba = *(const fvec4*)&smf[F_YB1 + ci * 32 + quad * 8];
            fvec4 bb = *(const fvec4*)&smf[F_YB1 + ci * 32 + quad * 8 + 4];
            fvec4 ga = *(const fvec4*)&smf[F_GB1 + ci * 32 + quad * 8];
            fvec4 gb = *(const fvec4*)&smf[F_GB1 + ci * 32 + quad * 8 + 4];
#pragma unroll
            for (int jj = 0; jj < 4; ++jj) {
                half2v w = upk(pa[jj]);
                w0f[jj] = (float)w[0];
                cc[jj]  = (float)w[1] * fb + ba[jj];
                b1g[jj] = ga[jj];
            }
#pragma unroll
            for (int jj = 0; jj < 4; ++jj) {
                half2v w = upk(pb[jj]);
                w0f[4 + jj] = (float)w[0];
                cc[4 + jj]  = (float)w[1] * fb + bb[jj];
                b1g[4 + jj] = gb[jj];
            }
        }
        // W2 A-fragments: A[m=col(+16)][k=quad*8..+7], direct from global
        const f16x8 Ay0 = load_row8(yW2, ci * 1024 + col * 32 + quad * 8, fmode);
        const f16x8 Ay1 = load_row8(yW2, ci * 1024 + (col + 16) * 32 + quad * 8, fmode);
        const f16x8 Ag0 = load_row8(gW2, ci * 1024 + col * 32 + quad * 8, fmode);
        const f16x8 Ag1 = load_row8(gW2, ci * 1024 + (col + 16) * 32 + quad * 8, fmode);
        const float b3y = smf[F_YB3 + ci];
        const float b3g = smf[F_GB3 + ci];

#pragma unroll 1
        for (int t = 0; t < 4; ++t) {
            const int pos = (wave * 4 + t) * 16 + col;
            const float fap = smf[F_FA + pos * 4 + ci];
            const unsigned km = smu[U_MASK + pos];
            const uvec4 gq = *(const uvec4*)&smu[UG_G + pos * 4];

            // ky L1 -> B-frag (B[k=quad*8+j][n=col])
            unsigned by0 = pk2u(silu_f(w0f[0] * fap + cc[0]), silu_f(w0f[1] * fap + cc[1]));
            unsigned by1 = pk2u(silu_f(w0f[2] * fap + cc[2]), silu_f(w0f[3] * fap + cc[3]));
            unsigned by2 = pk2u(silu_f(w0f[4] * fap + cc[4]), silu_f(w0f[5] * fap + cc[5]));
            unsigned by3 = pk2u(silu_f(w0f[6] * fap + cc[6]), silu_f(w0f[7] * fap + cc[7]));
            const f16x8 By = mk_frag(by0, by1, by2, by3);

            // kg L1 -> B-frag
            unsigned bg[4];
#pragma unroll
            for (int jj2 = 0; jj2 < 4; ++jj2) {
                float hh[2];
#pragma unroll
                for (int e = 0; e < 2; ++e) {
                    const int j1 = quad * 8 + 2 * jj2 + e;
                    uvec4 wr = *(const uvec4*)&smu[U_GW1 + ci * 128 + j1 * 4];
                    float tt = b1g[2 * jj2 + e];
                    tt = FDOT2(upk(wr[0]), upk(gq[0]), tt);
                    tt = FDOT2(upk(wr[1]), upk(gq[1]), tt);
                    tt = FDOT2(upk(wr[2]), upk(gq[2]), tt);
                    tt = FDOT2(upk(wr[3]), upk(gq[3]), tt);
                    hh[e] = silu_f(tt);
                }
                bg[jj2] = pk2u(hh[0], hh[1]);
            }
            const f16x8 Bg = mk_frag(bg[0], bg[1], bg[2], bg[3]);

            f32x4 dy0, dy1, dg0, dg1;
#if defined(__HIP_DEVICE_COMPILE__)
            dy0 = __builtin_amdgcn_mfma_f32_16x16x32_f16(Ay0, By, zf, 0, 0, 0);
            dy1 = __builtin_amdgcn_mfma_f32_16x16x32_f16(Ay1, By, zf, 0, 0, 0);
            dg0 = __builtin_amdgcn_mfma_f32_16x16x32_f16(Ag0, Bg, zf, 0, 0, 0);
            dg1 = __builtin_amdgcn_mfma_f32_16x16x32_f16(Ag1, Bg, zf, 0, 0, 0);
#else
            dy0 = zf; dy1 = zf; dg0 = zf; dg1 = zf;  // host parse only
#endif
            // post-L2 + L3: lane holds rows j2 = quad*4+r (+16 for tile 1)
            fvec4 b2y0 = *(const fvec4*)&smf[F_YB2 + ci * 32 + quad * 4];
            fvec4 b2y1 = *(const fvec4*)&smf[F_YB2 + ci * 32 + 16 + quad * 4];
            fvec4 w3y0 = *(const fvec4*)&smf[F_YW3 + ci * 32 + quad * 4];
            fvec4 w3y1 = *(const fvec4*)&smf[F_YW3 + ci * 32 + 16 + quad * 4];
            fvec4 b2g0 = *(const fvec4*)&smf[F_GB2 + ci * 32 + quad * 4];
            fvec4 b2g1 = *(const fvec4*)&smf[F_GB2 + ci * 32 + 16 + quad * 4];
            fvec4 w3g0 = *(const fvec4*)&smf[F_GW3 + ci * 32 + quad * 4];
            fvec4 w3g1 = *(const fvec4*)&smf[F_GW3 + ci * 32 + 16 + quad * 4];
            float a3y = 0.f, a3g = 0.f;
#pragma unroll
            for (int r = 0; r < 4; ++r) {
                a3y += w3y0[r] * silu_f(dy0[r] + b2y0[r]);
                a3y += w3y1[r] * silu_f(dy1[r] + b2y1[r]);
                a3g += w3g0[r] * silu_f(dg0[r] + b2g0[r]);
                a3g += w3g1[r] * silu_f(dg1[r] + b2g1[r]);
            }
            a3y += __shfl_xor(a3y, 16); a3y += __shfl_xor(a3y, 32);
            a3g += __shfl_xor(a3g, 16); a3g += __shfl_xor(a3g, 32);

            const float kyv = silu_f(a3y + b3y);
            const float kgv = silu_f(a3g + b3g);
            const float e = km ? exp_f(kyv + kgv) : 0.f;
            accD[ci] += e;
            accN[ci] += e * fap;
        }
    }

    // reduce across the 16 positions (lane bits 0-3; quads hold identical
    // copies after the xor-16/32 reduction)
#pragma unroll
    for (int ci = 0; ci < CIN; ++ci) {
        accN[ci] += __shfl_xor(accN[ci], 1);  accD[ci] += __shfl_xor(accD[ci], 1);
        accN[ci] += __shfl_xor(accN[ci], 2);  accD[ci] += __shfl_xor(accD[ci], 2);
        accN[ci] += __shfl_xor(accN[ci], 4);  accD[ci] += __shfl_xor(accD[ci], 4);
        accN[ci] += __shfl_xor(accN[ci], 8);  accD[ci] += __shfl_xor(accD[ci], 8);
    }
    if (lane == 0) {
#pragma unroll
        for (int ci = 0; ci < CIN; ++ci) {
            smf[F_RED + (wave * 4 + ci) * 2 + 0] = accN[ci];
            smf[F_RED + (wave * 4 + ci) * 2 + 1] = accD[ci];
        }
    }
    __syncthreads();

    if (tid < COUT) {
        const int o = tid;
        const unsigned m1 = smu[U_MASK + qpos];
        float acc = 0.f;
#pragma unroll
        for (int ci = 0; ci < CIN; ++ci) {
            float N = 0.f, D = 0.f;
#pragma unroll
            for (int w = 0; w < 8; ++w) {
                N += smf[F_RED + (w * 4 + ci) * 2 + 0];
                D += smf[F_RED + (w * 4 + ci) * 2 + 1];
            }
            const float fbv = smf[F_FA + qpos * 4 + ci];
            const float cf = m1 ? (fbv + N / D) : 0.f;
            acc += cf * loadS(wout, o * CIN + ci, fmode);
        }
        const int oidx = (bn * SS + s1) * COUT + o;
        if (fmode) ((__hip_bfloat16*)outp)[oidx] = __float2bfloat16(acc);
        else       ((float*)outp)[oidx] = acc;
    }
}

extern "C" void kernel_launch(void* const* d_in, const int* in_sizes, int n_in,
                              void* d_out, int out_size, void* d_ws, size_t ws_size,
                              hipStream_t stream) {
    emha_mfma<<<BB * NN * SS, NTHR, 0, stream>>>(
        d_in[0], d_in[1], d_in[2],
        d_in[3], d_in[4], d_in[5], d_in[6], d_in[7], d_in[8],
        d_in[9], d_in[10], d_in[11], d_in[12], d_in[13], d_in[14],
        d_in[15], d_out);
}

// Round 13
// 208.660 us; speedup vs baseline: 2.7782x; 2.7782x over previous
//
#include <hip/hip_runtime.h>
#include <hip/hip_bf16.h>

#define BB   2
#define NN   128
#define SS   4
#define DGG  8
#define CIN  4
#define COUT 8
#define HH   32
#define NTHR 512

typedef __attribute__((ext_vector_type(4))) float          fvec4;
typedef __attribute__((ext_vector_type(4))) unsigned short usvec4;
typedef __attribute__((ext_vector_type(8))) unsigned short usvec8;
typedef __attribute__((ext_vector_type(2))) __fp16         half2v;
typedef __attribute__((ext_vector_type(8))) __fp16         f16x8;
typedef __attribute__((ext_vector_type(4))) float          f32x4;
typedef __attribute__((ext_vector_type(4))) unsigned int   uvec4;

__device__ __forceinline__ float bf2f(unsigned short u) {
    return __uint_as_float(((unsigned int)u) << 16);
}
__device__ __forceinline__ float silu_f(float x) {
    float e = __builtin_amdgcn_exp2f(x * -1.44269504f);
    return x * __builtin_amdgcn_rcpf(1.0f + e);
}
__device__ __forceinline__ float exp_f(float x) {
    return __builtin_amdgcn_exp2f(x * 1.44269504f);
}

#if __has_builtin(__builtin_amdgcn_fdot2)
__device__ __forceinline__ float FDOT2(half2v a, half2v b, float c) {
    return __builtin_amdgcn_fdot2(a, b, c, false);
}
#else
__device__ __forceinline__ float FDOT2(half2v a, half2v b, float c) {
    return (float)a[0] * (float)b[0] + (float)a[1] * (float)b[1] + c;
}
#endif

__device__ __forceinline__ half2v upk(unsigned int u) {
    union { unsigned int u; half2v h; } x; x.u = u; return x.h;
}
__device__ __forceinline__ unsigned int pk2u(float a, float b) {
#if __has_builtin(__builtin_amdgcn_cvt_pkrtz)
    half2v h = __builtin_amdgcn_cvt_pkrtz(a, b);
#else
    half2v h; h[0] = (__fp16)a; h[1] = (__fp16)b;
#endif
    union { half2v h; unsigned int u; } x; x.h = h; return x.u;
}
union FU { uvec4 u; f16x8 h; };
__device__ __forceinline__ f16x8 mk_frag(unsigned a, unsigned b, unsigned c, unsigned d) {
    FU x; x.u = (uvec4){a, b, c, d}; return x.h;
}

__device__ __forceinline__ float loadS(const void* p, int idx, int fmode) {
    return fmode ? bf2f(((const unsigned short*)p)[idx])
                 : ((const float*)p)[idx];
}
__device__ __forceinline__ void load8(const void* p, int base, int fmode, float* dst) {
    if (fmode) {
        usvec8 v = *(const usvec8*)((const unsigned short*)p + base);
#pragma unroll
        for (int d = 0; d < 8; ++d) dst[d] = bf2f(v[d]);
    } else {
        fvec4 a = *(const fvec4*)((const float*)p + base);
        fvec4 b = *(const fvec4*)((const float*)p + base + 4);
        dst[0] = a[0]; dst[1] = a[1]; dst[2] = a[2]; dst[3] = a[3];
        dst[4] = b[0]; dst[5] = b[1]; dst[6] = b[2]; dst[7] = b[3];
    }
}
// 8 consecutive weights -> f16x8 MFMA fragment (element r = k offset r)
__device__ __forceinline__ f16x8 load_row8(const void* p, int eoff, int fmode) {
    unsigned u[4];
    if (fmode) {
        usvec8 v = *(const usvec8*)((const unsigned short*)p + eoff);
#pragma unroll
        for (int q = 0; q < 4; ++q) u[q] = pk2u(bf2f(v[2 * q]), bf2f(v[2 * q + 1]));
    } else {
        fvec4 a = *(const fvec4*)((const float*)p + eoff);
        fvec4 b = *(const fvec4*)((const float*)p + eoff + 4);
        u[0] = pk2u(a[0], a[1]); u[1] = pk2u(a[2], a[3]);
        u[2] = pk2u(b[0], b[1]); u[3] = pk2u(b[2], b[3]);
    }
    return mk_frag(u[0], u[1], u[2], u[3]);
}
__device__ __forceinline__ int load_mask(const void* p, int idx, int mmode) {
    if (mmode == 0) return ((const int*)p)[idx] != 0;
    if (mmode == 1) return ((const unsigned short*)p)[idx] != 0;
    if (mmode == 2) return ((const unsigned char*)p)[idx] != 0;
    return ((const unsigned int*)p)[idx] != 0;
}
__device__ __forceinline__ void stage_pk(unsigned int* dst, const void* src,
                                         int pairs, int fmode, int tid) {
    if (fmode) {
        const unsigned short* s = (const unsigned short*)src;
        for (int x = tid; x < pairs; x += NTHR)
            dst[x] = pk2u(bf2f(s[2 * x]), bf2f(s[2 * x + 1]));
    } else {
        const float* s = (const float*)src;
        for (int x = tid; x < pairs; x += NTHR)
            dst[x] = pk2u(s[2 * x], s[2 * x + 1]);
    }
}
__device__ __forceinline__ void copy_arr(float* sm, const void* src, int off,
                                         int cnt, int fmode, int tid) {
    if (fmode) {
        const unsigned short* s = (const unsigned short*)src;
        for (int x = tid; x < cnt; x += NTHR) sm[off + x] = bf2f(s[x]);
    } else {
        const float* s = (const float*)src;
        for (int x = tid; x < cnt; x += NTHR) sm[off + x] = s[x];
    }
}
// modes: [0]=float dtype (0=f32,1=bf16), [1]=mask dtype (0=i32,1=bf16,2=u8,3=f32)
__device__ __forceinline__ void detect_inline(const void* g_mask, const void* g_coset,
                                              int tid, int* smi, int slot) {
    if (tid < 64) {
        const unsigned short* cu = (const unsigned short*)g_coset;
        unsigned short v = cu[2 * tid];
        int e = (v >> 7) & 0xFF;
        int hits = __popcll(__ballot(e >= 110 && e <= 135));
        int fmode_ = (hits > 32) ? 1 : 0;
        const unsigned short* mu = (const unsigned short*)g_mask;
        int evenBF = 0, any3 = 0, anyByte = 0;
        for (int r = 0; r < 8; ++r) {
            int idx = tid + r * 64;
            unsigned short m = mu[idx];
            if (m == 0x3F80) { any3 = 1; if (!(idx & 1)) evenBF = 1; }
            if (m == 0x0101 || m == 0x0100) anyByte = 1;
        }
        evenBF  = (__ballot(evenBF)  != 0ull);
        any3    = (__ballot(any3)    != 0ull);
        anyByte = (__ballot(anyByte) != 0ull);
        if (tid == 0) {
            smi[slot]     = fmode_;
            smi[slot + 1] = evenBF ? 1 : (any3 ? 3 : (anyByte ? 2 : 0));
        }
    }
}

// LDS layout (u32 units)
#define UG_G    0      // 2048: pairwise_g slice for (bn,s1), packed f16 [pos][4]
#define F_FA    2048   // 2048 f32: coset b-slice [pos2=n*4+s][ci]
#define U_MASK  4096   // 512: key mask per pos (0/1)
#define U_YW1   4608   // 128 pairs (w0,w1) per (ci,j1)
#define U_GW1   4736   // 512 pairs: [ci][j1][4]
#define F_YB1   5248   // 128
#define F_YB2   5376   // 128
#define F_YW3   5504   // 128
#define F_GB1   5632   // 128
#define F_GB2   5760   // 128
#define F_GW3   5888   // 128
#define F_YB3   6016   // 4
#define F_GB3   6020   // 4
#define F_RED   6024   // 64: [8 waves][4 ci][N,D]
#define F_MODE  6088   // 2
#define U_TOTAL 6090   // ~24.4 KB

// One block per (bn, s1); 512 threads = 8 waves; each wave handles 4
// position-tiles of 16.  Body is the round-10 per-tile chain (compiles to
// 64 VGPR naturally).  ROUND-13 FIX vs round 12: __launch_bounds__(512,4)
// (cap 128 VGPR) — round-12's (512,8) forced VGPR=32 and spilled 746 MB to
// scratch (VALUBusy 15%).  The spill-cliff rule: this body needs >=64 VGPRs;
// never bound below that.  With natural 64-VGPR allocation the HW can still
// co-schedule 8 waves/EU from the 4 resident blocks/CU (LDS 24.4KB x 4 fits).
__global__ __launch_bounds__(NTHR, 4) void emha_mfma(
    const void* __restrict__ g_pw, const void* __restrict__ g_coset,
    const void* __restrict__ g_mask,
    const void* yW1, const void* yb1, const void* yW2, const void* yb2,
    const void* yW3, const void* yb3,
    const void* gW1, const void* gb1, const void* gW2, const void* gb2,
    const void* gW3, const void* gb3,
    const void* wout, void* outp)
{
    __shared__ unsigned int smu[U_TOTAL];
    float* smf = (float*)smu;
    int*   smi = (int*)smu;
    const int tid = threadIdx.x;

    detect_inline(g_mask, g_coset, tid, smi, F_MODE);
    __syncthreads();
    const int fmode = smi[F_MODE];
    const int mmode = smi[F_MODE + 1];
    __syncthreads();

    const int bn = blockIdx.x >> 2;   // b*128 + n1
    const int s1 = blockIdx.x & 3;
    const int b  = bn >> 7;
    const int n1 = bn & 127;

    // ---- stage pairwise_g slice (pos = n2*4+s2), packed f16, b128 writes ----
    {
        const int pos = tid;          // 512 threads cover all 512 positions
        const int n2 = pos >> 2, s2 = pos & 3;
        float g8[8];
        load8(g_pw, (((bn * NN + n2) * SS + s1) * SS + s2) * DGG, fmode, g8);
        uvec4 gp;
#pragma unroll
        for (int q = 0; q < 4; ++q) gp[q] = pk2u(g8[2 * q], g8[2 * q + 1]);
        *(uvec4*)&smu[UG_G + pos * 4] = gp;
    }
    // ---- stage coset b-slice (f32) and key mask ----
    for (int x = tid; x < 2048; x += NTHR)
        smf[F_FA + x] = loadS(g_coset, b * 2048 + x, fmode);
    smu[U_MASK + tid] = (unsigned)load_mask(g_mask, b * 512 + tid, mmode);
    // ---- stage W1s (packed pairs) + biases/w3 (f32) ----
    stage_pk(&smu[U_YW1], yW1, 128, fmode, tid);
    stage_pk(&smu[U_GW1], gW1, 512, fmode, tid);
    copy_arr(smf, yb1, F_YB1, 128, fmode, tid);
    copy_arr(smf, yb2, F_YB2, 128, fmode, tid);
    copy_arr(smf, yW3, F_YW3, 128, fmode, tid);
    copy_arr(smf, gb1, F_GB1, 128, fmode, tid);
    copy_arr(smf, gb2, F_GB2, 128, fmode, tid);
    copy_arr(smf, gW3, F_GW3, 128, fmode, tid);
    copy_arr(smf, yb3, F_YB3, 4, fmode, tid);
    copy_arr(smf, gb3, F_GB3, 4, fmode, tid);
    __syncthreads();

    const int lane = tid & 63;
    const int wave = tid >> 6;        // [0,8)
    const int quad = lane >> 4;
    const int col  = lane & 15;
    const int qpos = n1 * 4 + s1;     // query index in b-slice

    float accN[4] = {0.f, 0.f, 0.f, 0.f};
    float accD[4] = {0.f, 0.f, 0.f, 0.f};
    const f32x4 zf = {0.f, 0.f, 0.f, 0.f};

#pragma unroll
    for (int ci = 0; ci < CIN; ++ci) {
        const float fb = smf[F_FA + qpos * 4 + ci];
        // ky L1 constants for this lane's 8 j1 rows (j1 = quad*8 + jj)
        float w0f[8], cc[8], b1g[8];
        {
            uvec4 pa = *(const uvec4*)&smu[U_YW1 + ci * 32 + quad * 8];
            uvec4 pb = *(const uvec4*)&smu[U_YW1 + ci * 32 + quad * 8 + 4];
            fvec4 ba = *(const fvec4*)&smf[F_YB1 + ci * 32 + quad * 8];
            fvec4 bb = *(const fvec4*)&smf[F_YB1 + ci * 32 + quad * 8 + 4];
            fvec4 ga = *(const fvec4*)&smf[F_GB1 + ci * 32 + quad * 8];
            fvec4 gb = *(const fvec4*)&smf[F_GB1 + ci * 32 + quad * 8 + 4];
#pragma unroll
            for (int jj = 0; jj < 4; ++jj) {
                half2v w = upk(pa[jj]);
                w0f[jj] = (float)w[0];
                cc[jj]  = (float)w[1] * fb + ba[jj];
                b1g[jj] = ga[jj];
            }
#pragma unroll
            for (int jj = 0; jj < 4; ++jj) {
                half2v w = upk(pb[jj]);
                w0f[4 + jj] = (float)w[0];
                cc[4 + jj]  = (float)w[1] * fb + bb[jj];
                b1g[4 + jj] = gb[jj];
            }
        }
        // W2 A-fragments: A[m=col(+16)][k=quad*8..+7], direct from global
        const f16x8 Ay0 = load_row8(yW2, ci * 1024 + col * 32 + quad * 8, fmode);
        const f16x8 Ay1 = load_row8(yW2, ci * 1024 + (col + 16) * 32 + quad * 8, fmode);
        const f16x8 Ag0 = load_row8(gW2, ci * 1024 + col * 32 + quad * 8, fmode);
        const f16x8 Ag1 = load_row8(gW2, ci * 1024 + (col + 16) * 32 + quad * 8, fmode);
        const float b3y = smf[F_YB3 + ci];
        const float b3g = smf[F_GB3 + ci];

#pragma unroll 1
        for (int t = 0; t < 4; ++t) {
            const int pos = (wave * 4 + t) * 16 + col;
            const float fap = smf[F_FA + pos * 4 + ci];
            const unsigned km = smu[U_MASK + pos];
            const uvec4 gq = *(const uvec4*)&smu[UG_G + pos * 4];

            // ky L1 -> B-frag (B[k=quad*8+j][n=col])
            unsigned by0 = pk2u(silu_f(w0f[0] * fap + cc[0]), silu_f(w0f[1] * fap + cc[1]));
            unsigned by1 = pk2u(silu_f(w0f[2] * fap + cc[2]), silu_f(w0f[3] * fap + cc[3]));
            unsigned by2 = pk2u(silu_f(w0f[4] * fap + cc[4]), silu_f(w0f[5] * fap + cc[5]));
            unsigned by3 = pk2u(silu_f(w0f[6] * fap + cc[6]), silu_f(w0f[7] * fap + cc[7]));
            const f16x8 By = mk_frag(by0, by1, by2, by3);

            // kg L1 -> B-frag
            unsigned bg[4];
#pragma unroll
            for (int jj2 = 0; jj2 < 4; ++jj2) {
                float hh[2];
#pragma unroll
                for (int e = 0; e < 2; ++e) {
                    const int j1 = quad * 8 + 2 * jj2 + e;
                    uvec4 wr = *(const uvec4*)&smu[U_GW1 + ci * 128 + j1 * 4];
                    float tt = b1g[2 * jj2 + e];
                    tt = FDOT2(upk(wr[0]), upk(gq[0]), tt);
                    tt = FDOT2(upk(wr[1]), upk(gq[1]), tt);
                    tt = FDOT2(upk(wr[2]), upk(gq[2]), tt);
                    tt = FDOT2(upk(wr[3]), upk(gq[3]), tt);
                    hh[e] = silu_f(tt);
                }
                bg[jj2] = pk2u(hh[0], hh[1]);
            }
            const f16x8 Bg = mk_frag(bg[0], bg[1], bg[2], bg[3]);

            f32x4 dy0, dy1, dg0, dg1;
#if defined(__HIP_DEVICE_COMPILE__)
            dy0 = __builtin_amdgcn_mfma_f32_16x16x32_f16(Ay0, By, zf, 0, 0, 0);
            dy1 = __builtin_amdgcn_mfma_f32_16x16x32_f16(Ay1, By, zf, 0, 0, 0);
            dg0 = __builtin_amdgcn_mfma_f32_16x16x32_f16(Ag0, Bg, zf, 0, 0, 0);
            dg1 = __builtin_amdgcn_mfma_f32_16x16x32_f16(Ag1, Bg, zf, 0, 0, 0);
#else
            dy0 = zf; dy1 = zf; dg0 = zf; dg1 = zf;  // host parse only
#endif
            // post-L2 + L3: lane holds rows j2 = quad*4+r (+16 for tile 1)
            fvec4 b2y0 = *(const fvec4*)&smf[F_YB2 + ci * 32 + quad * 4];
            fvec4 b2y1 = *(const fvec4*)&smf[F_YB2 + ci * 32 + 16 + quad * 4];
            fvec4 w3y0 = *(const fvec4*)&smf[F_YW3 + ci * 32 + quad * 4];
            fvec4 w3y1 = *(const fvec4*)&smf[F_YW3 + ci * 32 + 16 + quad * 4];
            fvec4 b2g0 = *(const fvec4*)&smf[F_GB2 + ci * 32 + quad * 4];
            fvec4 b2g1 = *(const fvec4*)&smf[F_GB2 + ci * 32 + 16 + quad * 4];
            fvec4 w3g0 = *(const fvec4*)&smf[F_GW3 + ci * 32 + quad * 4];
            fvec4 w3g1 = *(const fvec4*)&smf[F_GW3 + ci * 32 + 16 + quad * 4];
            float a3y = 0.f, a3g = 0.f;
#pragma unroll
            for (int r = 0; r < 4; ++r) {
                a3y += w3y0[r] * silu_f(dy0[r] + b2y0[r]);
                a3y += w3y1[r] * silu_f(dy1[r] + b2y1[r]);
                a3g += w3g0[r] * silu_f(dg0[r] + b2g0[r]);
                a3g += w3g1[r] * silu_f(dg1[r] + b2g1[r]);
            }
            a3y += __shfl_xor(a3y, 16); a3y += __shfl_xor(a3y, 32);
            a3g += __shfl_xor(a3g, 16); a3g += __shfl_xor(a3g, 32);

            const float kyv = silu_f(a3y + b3y);
            const float kgv = silu_f(a3g + b3g);
            const float e = km ? exp_f(kyv + kgv) : 0.f;
            accD[ci] += e;
            accN[ci] += e * fap;
        }
    }

    // reduce across the 16 positions (lane bits 0-3; quads hold identical
    // copies after the xor-16/32 reduction)
#pragma unroll
    for (int ci = 0; ci < CIN; ++ci) {
        accN[ci] += __shfl_xor(accN[ci], 1);  accD[ci] += __shfl_xor(accD[ci], 1);
        accN[ci] += __shfl_xor(accN[ci], 2);  accD[ci] += __shfl_xor(accD[ci], 2);
        accN[ci] += __shfl_xor(accN[ci], 4);  accD[ci] += __shfl_xor(accD[ci], 4);
        accN[ci] += __shfl_xor(accN[ci], 8);  accD[ci] += __shfl_xor(accD[ci], 8);
    }
    if (lane == 0) {
#pragma unroll
        for (int ci = 0; ci < CIN; ++ci) {
            smf[F_RED + (wave * 4 + ci) * 2 + 0] = accN[ci];
            smf[F_RED + (wave * 4 + ci) * 2 + 1] = accD[ci];
        }
    }
    __syncthreads();

    if (tid < COUT) {
        const int o = tid;
        const unsigned m1 = smu[U_MASK + qpos];
        float acc = 0.f;
#pragma unroll
        for (int ci = 0; ci < CIN; ++ci) {
            float N = 0.f, D = 0.f;
#pragma unroll
            for (int w = 0; w < 8; ++w) {
                N += smf[F_RED + (w * 4 + ci) * 2 + 0];
                D += smf[F_RED + (w * 4 + ci) * 2 + 1];
            }
            const float fbv = smf[F_FA + qpos * 4 + ci];
            const float cf = m1 ? (fbv + N / D) : 0.f;
            acc += cf * loadS(wout, o * CIN + ci, fmode);
        }
        const int oidx = (bn * SS + s1) * COUT + o;
        if (fmode) ((__hip_bfloat16*)outp)[oidx] = __float2bfloat16(acc);
        else       ((float*)outp)[oidx] = acc;
    }
}

extern "C" void kernel_launch(void* const* d_in, const int* in_sizes, int n_in,
                              void* d_out, int out_size, void* d_ws, size_t ws_size,
                              hipStream_t stream) {
    emha_mfma<<<BB * NN * SS, NTHR, 0, stream>>>(
        d_in[0], d_in[1], d_in[2],
        d_in[3], d_in[4], d_in[5], d_in[6], d_in[7], d_in[8],
        d_in[9], d_in[10], d_in[11], d_in[12], d_in[13], d_in[14],
        d_in[15], d_out);
}

// Round 14
// 196.557 us; speedup vs baseline: 2.9492x; 1.0616x over previous
//
#include <hip/hip_runtime.h>
#include <hip/hip_bf16.h>

#define BB   2
#define NN   128
#define SS   4
#define DGG  8
#define CIN  4
#define COUT 8
#define HH   32

typedef __attribute__((ext_vector_type(4))) float          fvec4;
typedef __attribute__((ext_vector_type(4))) unsigned short usvec4;
typedef __attribute__((ext_vector_type(8))) unsigned short usvec8;
typedef __attribute__((ext_vector_type(2))) __fp16         half2v;
typedef __attribute__((ext_vector_type(8))) __fp16         f16x8;
typedef __attribute__((ext_vector_type(4))) float          f32x4;
typedef __attribute__((ext_vector_type(4))) unsigned int   uvec4;

__device__ __forceinline__ float bf2f(unsigned short u) {
    return __uint_as_float(((unsigned int)u) << 16);
}
__device__ __forceinline__ float silu_f(float x) {
    float e = __builtin_amdgcn_exp2f(x * -1.44269504f);
    return x * __builtin_amdgcn_rcpf(1.0f + e);
}
__device__ __forceinline__ float exp_f(float x) {
    return __builtin_amdgcn_exp2f(x * 1.44269504f);
}

#if __has_builtin(__builtin_amdgcn_fdot2)
__device__ __forceinline__ float FDOT2(half2v a, half2v b, float c) {
    return __builtin_amdgcn_fdot2(a, b, c, false);
}
#else
__device__ __forceinline__ float FDOT2(half2v a, half2v b, float c) {
    return (float)a[0] * (float)b[0] + (float)a[1] * (float)b[1] + c;
}
#endif

__device__ __forceinline__ half2v upk(unsigned int u) {
    union { unsigned int u; half2v h; } x; x.u = u; return x.h;
}
__device__ __forceinline__ unsigned int pk2u(float a, float b) {
#if __has_builtin(__builtin_amdgcn_cvt_pkrtz)
    half2v h = __builtin_amdgcn_cvt_pkrtz(a, b);
#else
    half2v h; h[0] = (__fp16)a; h[1] = (__fp16)b;
#endif
    union { half2v h; unsigned int u; } x; x.h = h; return x.u;
}
union FU { uvec4 u; f16x8 h; };
__device__ __forceinline__ f16x8 mk_frag(unsigned a, unsigned b, unsigned c, unsigned d) {
    FU x; x.u = (uvec4){a, b, c, d}; return x.h;
}

__device__ __forceinline__ float loadS(const void* p, int idx, int fmode) {
    return fmode ? bf2f(((const unsigned short*)p)[idx])
                 : ((const float*)p)[idx];
}
__device__ __forceinline__ void load8(const void* p, int base, int fmode, float* dst) {
    if (fmode) {
        usvec8 v = *(const usvec8*)((const unsigned short*)p + base);
#pragma unroll
        for (int d = 0; d < 8; ++d) dst[d] = bf2f(v[d]);
    } else {
        fvec4 a = *(const fvec4*)((const float*)p + base);
        fvec4 b = *(const fvec4*)((const float*)p + base + 4);
        dst[0] = a[0]; dst[1] = a[1]; dst[2] = a[2]; dst[3] = a[3];
        dst[4] = b[0]; dst[5] = b[1]; dst[6] = b[2]; dst[7] = b[3];
    }
}
// 8 consecutive weights -> f16x8 MFMA fragment (element r = k offset r)
__device__ __forceinline__ f16x8 load_row8(const void* p, int eoff, int fmode) {
    unsigned u[4];
    if (fmode) {
        usvec8 v = *(const usvec8*)((const unsigned short*)p + eoff);
#pragma unroll
        for (int q = 0; q < 4; ++q) u[q] = pk2u(bf2f(v[2 * q]), bf2f(v[2 * q + 1]));
    } else {
        fvec4 a = *(const fvec4*)((const float*)p + eoff);
        fvec4 b = *(const fvec4*)((const float*)p + eoff + 4);
        u[0] = pk2u(a[0], a[1]); u[1] = pk2u(a[2], a[3]);
        u[2] = pk2u(b[0], b[1]); u[3] = pk2u(b[2], b[3]);
    }
    return mk_frag(u[0], u[1], u[2], u[3]);
}
__device__ __forceinline__ int load_mask(const void* p, int idx, int mmode) {
    if (mmode == 0) return ((const int*)p)[idx] != 0;
    if (mmode == 1) return ((const unsigned short*)p)[idx] != 0;
    if (mmode == 2) return ((const unsigned char*)p)[idx] != 0;
    return ((const unsigned int*)p)[idx] != 0;
}
__device__ __forceinline__ void stage_pk(unsigned int* dst, const void* src,
                                         int pairs, int fmode, int tid) {
    if (fmode) {
        const unsigned short* s = (const unsigned short*)src;
        for (int x = tid; x < pairs; x += 256)
            dst[x] = pk2u(bf2f(s[2 * x]), bf2f(s[2 * x + 1]));
    } else {
        const float* s = (const float*)src;
        for (int x = tid; x < pairs; x += 256)
            dst[x] = pk2u(s[2 * x], s[2 * x + 1]);
    }
}
__device__ __forceinline__ void copy_arr(float* sm, const void* src, int off,
                                         int cnt, int fmode, int tid) {
    if (fmode) {
        const unsigned short* s = (const unsigned short*)src;
        for (int x = tid; x < cnt; x += 256) sm[off + x] = bf2f(s[x]);
    } else {
        const float* s = (const float*)src;
        for (int x = tid; x < cnt; x += 256) sm[off + x] = s[x];
    }
}
// modes: [0]=float dtype (0=f32,1=bf16), [1]=mask dtype (0=i32,1=bf16,2=u8,3=f32)
__device__ __forceinline__ void detect_inline(const void* g_mask, const void* g_coset,
                                              int tid, int* smi, int slot) {
    if (tid < 64) {
        const unsigned short* cu = (const unsigned short*)g_coset;
        unsigned short v = cu[2 * tid];
        int e = (v >> 7) & 0xFF;
        int hits = __popcll(__ballot(e >= 110 && e <= 135));
        int fmode_ = (hits > 32) ? 1 : 0;
        const unsigned short* mu = (const unsigned short*)g_mask;
        int evenBF = 0, any3 = 0, anyByte = 0;
        for (int r = 0; r < 8; ++r) {
            int idx = tid + r * 64;
            unsigned short m = mu[idx];
            if (m == 0x3F80) { any3 = 1; if (!(idx & 1)) evenBF = 1; }
            if (m == 0x0101 || m == 0x0100) anyByte = 1;
        }
        evenBF  = (__ballot(evenBF)  != 0ull);
        any3    = (__ballot(any3)    != 0ull);
        anyByte = (__ballot(anyByte) != 0ull);
        if (tid == 0) {
            smi[slot]     = fmode_;
            smi[slot + 1] = evenBF ? 1 : (any3 ? 3 : (anyByte ? 2 : 0));
        }
    }
}

// LDS layout (u32 units)
#define UG_G    0      // 2048: pairwise_g slice for (bn,s1), packed f16 [pos][4]
#define F_FA    2048   // 2048 f32: coset b-slice [pos2=n*4+s][ci]
#define U_MASK  4096   // 512: key mask per pos (0/1)
#define U_YW1   4608   // 128 pairs (w0,w1) per (ci,j1)
#define U_GW1   4736   // 512 pairs: [ci][j1][4]
#define F_YB1   5248   // 128
#define F_YB2   5376   // 128
#define F_YW3   5504   // 128
#define F_GB1   5632   // 128
#define F_GB2   5760   // 128
#define F_GW3   5888   // 128
#define F_YB3   6016   // 4
#define F_GB3   6020   // 4
#define F_RED   6024   // 32: [wave][ci][N,D]
#define F_MODE  6056   // 2
#define U_TOTAL 6058   // ~24.2 KB

// FINAL (round-10 configuration, best measured: kernel 127us / total 195us).
// One block per (bn, s1); 256 threads = 4 waves; wave handles 8 position-
// tiles of 16.  L1 MLPs computed per-lane directly in MFMA B-layout
// (B[k=quad*8+j][n=lane&15]); W2 in A-frags (A[m=lane&15][k=quad*8+j],
// loaded once per channel from global); L2 GEMMs on v_mfma_f32_16x16x32_f16
// (C/D: row=quad*4+reg, col=lane&15 — verified); L3 via per-lane fma +
// shfl_xor(16,32).  Block owns the whole (n2,s2) softmax reduction and
// writes its 8 outputs directly (no workspace, no finalize launch).
//
// Session-derived constraints that pin this exact shape (each violation
// measured as a regression):
//  - body needs its natural 64 VGPRs: any unroll/hoist/launch-bounds change
//    that adds live state or caps registers crosses the spill cliff
//    (R11: 199us, R12: 504us, R13: 139us)
//  - 256-thread blocks: 512-thread codegen of the same body spills (R13)
//  - scalar b32 LDS weight reads outperform b128 here (R8: 172us)
//  - coarse blocks beat fine-split blocks: fixed staging costs dominate
//    thin bodies (R7: 210us)
__global__ __launch_bounds__(256, 4) void emha_mfma(
    const void* __restrict__ g_pw, const void* __restrict__ g_coset,
    const void* __restrict__ g_mask,
    const void* yW1, const void* yb1, const void* yW2, const void* yb2,
    const void* yW3, const void* yb3,
    const void* gW1, const void* gb1, const void* gW2, const void* gb2,
    const void* gW3, const void* gb3,
    const void* wout, void* outp)
{
    __shared__ unsigned int smu[U_TOTAL];
    float* smf = (float*)smu;
    int*   smi = (int*)smu;
    const int tid = threadIdx.x;

    detect_inline(g_mask, g_coset, tid, smi, F_MODE);
    __syncthreads();
    const int fmode = smi[F_MODE];
    const int mmode = smi[F_MODE + 1];
    __syncthreads();

    const int bn = blockIdx.x >> 2;   // b*128 + n1
    const int s1 = blockIdx.x & 3;
    const int b  = bn >> 7;
    const int n1 = bn & 127;

    // ---- stage pairwise_g slice (pos = n2*4+s2), packed f16 ----
#pragma unroll
    for (int it = 0; it < 2; ++it) {
        const int pos = tid + it * 256;
        const int n2 = pos >> 2, s2 = pos & 3;
        float g8[8];
        load8(g_pw, (((bn * NN + n2) * SS + s1) * SS + s2) * DGG, fmode, g8);
#pragma unroll
        for (int q = 0; q < 4; ++q)
            smu[UG_G + pos * 4 + q] = pk2u(g8[2 * q], g8[2 * q + 1]);
    }
    // ---- stage coset b-slice (f32) and key mask ----
    for (int x = tid; x < 2048; x += 256)
        smf[F_FA + x] = loadS(g_coset, b * 2048 + x, fmode);
    for (int x = tid; x < 512; x += 256)
        smu[U_MASK + x] = (unsigned)load_mask(g_mask, b * 512 + x, mmode);
    // ---- stage W1s (packed pairs) + biases/w3 (f32) ----
    stage_pk(&smu[U_YW1], yW1, 128, fmode, tid);
    stage_pk(&smu[U_GW1], gW1, 512, fmode, tid);
    copy_arr(smf, yb1, F_YB1, 128, fmode, tid);
    copy_arr(smf, yb2, F_YB2, 128, fmode, tid);
    copy_arr(smf, yW3, F_YW3, 128, fmode, tid);
    copy_arr(smf, gb1, F_GB1, 128, fmode, tid);
    copy_arr(smf, gb2, F_GB2, 128, fmode, tid);
    copy_arr(smf, gW3, F_GW3, 128, fmode, tid);
    copy_arr(smf, yb3, F_YB3, 4, fmode, tid);
    copy_arr(smf, gb3, F_GB3, 4, fmode, tid);
    __syncthreads();

    const int lane = tid & 63;
    const int wave = tid >> 6;
    const int quad = lane >> 4;
    const int col  = lane & 15;
    const int qpos = n1 * 4 + s1;     // query index in b-slice

    float accN[4] = {0.f, 0.f, 0.f, 0.f};
    float accD[4] = {0.f, 0.f, 0.f, 0.f};
    const f32x4 zf = {0.f, 0.f, 0.f, 0.f};

#pragma unroll
    for (int ci = 0; ci < CIN; ++ci) {
        const float fb = smf[F_FA + qpos * 4 + ci];
        // ky L1 constants for this lane's 8 j1 rows (j1 = quad*8 + jj)
        float w0f[8], cc[8], b1g[8];
        {
            uvec4 pa = *(const uvec4*)&smu[U_YW1 + ci * 32 + quad * 8];
            uvec4 pb = *(const uvec4*)&smu[U_YW1 + ci * 32 + quad * 8 + 4];
            fvec4 ba = *(const fvec4*)&smf[F_YB1 + ci * 32 + quad * 8];
            fvec4 bb = *(const fvec4*)&smf[F_YB1 + ci * 32 + quad * 8 + 4];
            fvec4 ga = *(const fvec4*)&smf[F_GB1 + ci * 32 + quad * 8];
            fvec4 gb = *(const fvec4*)&smf[F_GB1 + ci * 32 + quad * 8 + 4];
#pragma unroll
            for (int jj = 0; jj < 4; ++jj) {
                half2v w = upk(pa[jj]);
                w0f[jj] = (float)w[0];
                cc[jj]  = (float)w[1] * fb + ba[jj];
                b1g[jj] = ga[jj];
            }
#pragma unroll
            for (int jj = 0; jj < 4; ++jj) {
                half2v w = upk(pb[jj]);
                w0f[4 + jj] = (float)w[0];
                cc[4 + jj]  = (float)w[1] * fb + bb[jj];
                b1g[4 + jj] = gb[jj];
            }
        }
        // W2 A-fragments: A[m=col(+16)][k=quad*8..+7], direct from global
        const f16x8 Ay0 = load_row8(yW2, ci * 1024 + col * 32 + quad * 8, fmode);
        const f16x8 Ay1 = load_row8(yW2, ci * 1024 + (col + 16) * 32 + quad * 8, fmode);
        const f16x8 Ag0 = load_row8(gW2, ci * 1024 + col * 32 + quad * 8, fmode);
        const f16x8 Ag1 = load_row8(gW2, ci * 1024 + (col + 16) * 32 + quad * 8, fmode);
        const float b3y = smf[F_YB3 + ci];
        const float b3g = smf[F_GB3 + ci];

#pragma unroll 1
        for (int t = 0; t < 8; ++t) {
            const int pos = (wave * 8 + t) * 16 + col;
            const float fap = smf[F_FA + pos * 4 + ci];
            const unsigned km = smu[U_MASK + pos];
            const uvec4 gq = *(const uvec4*)&smu[UG_G + pos * 4];

            // ky L1 -> B-frag (B[k=quad*8+j][n=col])
            unsigned by0 = pk2u(silu_f(w0f[0] * fap + cc[0]), silu_f(w0f[1] * fap + cc[1]));
            unsigned by1 = pk2u(silu_f(w0f[2] * fap + cc[2]), silu_f(w0f[3] * fap + cc[3]));
            unsigned by2 = pk2u(silu_f(w0f[4] * fap + cc[4]), silu_f(w0f[5] * fap + cc[5]));
            unsigned by3 = pk2u(silu_f(w0f[6] * fap + cc[6]), silu_f(w0f[7] * fap + cc[7]));
            const f16x8 By = mk_frag(by0, by1, by2, by3);

            // kg L1 -> B-frag
            unsigned bg[4];
#pragma unroll
            for (int jj2 = 0; jj2 < 4; ++jj2) {
                float hh[2];
#pragma unroll
                for (int e = 0; e < 2; ++e) {
                    const int j1 = quad * 8 + 2 * jj2 + e;
                    uvec4 wr = *(const uvec4*)&smu[U_GW1 + ci * 128 + j1 * 4];
                    float tt = b1g[2 * jj2 + e];
                    tt = FDOT2(upk(wr[0]), upk(gq[0]), tt);
                    tt = FDOT2(upk(wr[1]), upk(gq[1]), tt);
                    tt = FDOT2(upk(wr[2]), upk(gq[2]), tt);
                    tt = FDOT2(upk(wr[3]), upk(gq[3]), tt);
                    hh[e] = silu_f(tt);
                }
                bg[jj2] = pk2u(hh[0], hh[1]);
            }
            const f16x8 Bg = mk_frag(bg[0], bg[1], bg[2], bg[3]);

            f32x4 dy0, dy1, dg0, dg1;
#if defined(__HIP_DEVICE_COMPILE__)
            dy0 = __builtin_amdgcn_mfma_f32_16x16x32_f16(Ay0, By, zf, 0, 0, 0);
            dy1 = __builtin_amdgcn_mfma_f32_16x16x32_f16(Ay1, By, zf, 0, 0, 0);
            dg0 = __builtin_amdgcn_mfma_f32_16x16x32_f16(Ag0, Bg, zf, 0, 0, 0);
            dg1 = __builtin_amdgcn_mfma_f32_16x16x32_f16(Ag1, Bg, zf, 0, 0, 0);
#else
            dy0 = zf; dy1 = zf; dg0 = zf; dg1 = zf;  // host parse only
#endif
            // post-L2 + L3: lane holds rows j2 = quad*4+r (+16 for tile 1)
            fvec4 b2y0 = *(const fvec4*)&smf[F_YB2 + ci * 32 + quad * 4];
            fvec4 b2y1 = *(const fvec4*)&smf[F_YB2 + ci * 32 + 16 + quad * 4];
            fvec4 w3y0 = *(const fvec4*)&smf[F_YW3 + ci * 32 + quad * 4];
            fvec4 w3y1 = *(const fvec4*)&smf[F_YW3 + ci * 32 + 16 + quad * 4];
            fvec4 b2g0 = *(const fvec4*)&smf[F_GB2 + ci * 32 + quad * 4];
            fvec4 b2g1 = *(const fvec4*)&smf[F_GB2 + ci * 32 + 16 + quad * 4];
            fvec4 w3g0 = *(const fvec4*)&smf[F_GW3 + ci * 32 + quad * 4];
            fvec4 w3g1 = *(const fvec4*)&smf[F_GW3 + ci * 32 + 16 + quad * 4];
            float a3y = 0.f, a3g = 0.f;
#pragma unroll
            for (int r = 0; r < 4; ++r) {
                a3y += w3y0[r] * silu_f(dy0[r] + b2y0[r]);
                a3y += w3y1[r] * silu_f(dy1[r] + b2y1[r]);
                a3g += w3g0[r] * silu_f(dg0[r] + b2g0[r]);
                a3g += w3g1[r] * silu_f(dg1[r] + b2g1[r]);
            }
            a3y += __shfl_xor(a3y, 16); a3y += __shfl_xor(a3y, 32);
            a3g += __shfl_xor(a3g, 16); a3g += __shfl_xor(a3g, 32);

            const float kyv = silu_f(a3y + b3y);
            const float kgv = silu_f(a3g + b3g);
            const float e = km ? exp_f(kyv + kgv) : 0.f;
            accD[ci] += e;
            accN[ci] += e * fap;
        }
    }

    // reduce across the 16 positions (lane bits 0-3; quads hold identical
    // copies after the xor-16/32 reduction)
#pragma unroll
    for (int ci = 0; ci < CIN; ++ci) {
        accN[ci] += __shfl_xor(accN[ci], 1);  accD[ci] += __shfl_xor(accD[ci], 1);
        accN[ci] += __shfl_xor(accN[ci], 2);  accD[ci] += __shfl_xor(accD[ci], 2);
        accN[ci] += __shfl_xor(accN[ci], 4);  accD[ci] += __shfl_xor(accD[ci], 4);
        accN[ci] += __shfl_xor(accN[ci], 8);  accD[ci] += __shfl_xor(accD[ci], 8);
    }
    if (lane == 0) {
#pragma unroll
        for (int ci = 0; ci < CIN; ++ci) {
            smf[F_RED + (wave * 4 + ci) * 2 + 0] = accN[ci];
            smf[F_RED + (wave * 4 + ci) * 2 + 1] = accD[ci];
        }
    }
    __syncthreads();

    if (tid < COUT) {
        const int o = tid;
        const unsigned m1 = smu[U_MASK + qpos];
        float acc = 0.f;
#pragma unroll
        for (int ci = 0; ci < CIN; ++ci) {
            float N = 0.f, D = 0.f;
#pragma unroll
            for (int w = 0; w < 4; ++w) {
                N += smf[F_RED + (w * 4 + ci) * 2 + 0];
                D += smf[F_RED + (w * 4 + ci) * 2 + 1];
            }
            const float fbv = smf[F_FA + qpos * 4 + ci];
            const float cf = m1 ? (fbv + N / D) : 0.f;
            acc += cf * loadS(wout, o * CIN + ci, fmode);
        }
        const int oidx = (bn * SS + s1) * COUT + o;
        if (fmode) ((__hip_bfloat16*)outp)[oidx] = __float2bfloat16(acc);
        else       ((float*)outp)[oidx] = acc;
    }
}

extern "C" void kernel_launch(void* const* d_in, const int* in_sizes, int n_in,
                              void* d_out, int out_size, void* d_ws, size_t ws_size,
                              hipStream_t stream) {
    emha_mfma<<<BB * NN * SS, 256, 0, stream>>>(
        d_in[0], d_in[1], d_in[2],
        d_in[3], d_in[4], d_in[5], d_in[6], d_in[7], d_in[8],
        d_in[9], d_in[10], d_in[11], d_in[12], d_in[13], d_in[14],
        d_in[15], d_out);
}